// Round 7
// baseline (340.406 us; speedup 1.0000x reference)
//
#include <hip/hip_runtime.h>

#define BS 32
#define NA 8400
#define NMAX 100
#define NC 80
#define TOPK 13
#define EPSF 1e-9f
#define WCAP 1024    // per-wave candidate cap; true max ~400 (mean ~60)
#define NSTRIP 64
#define STRIP_INV 0.1f   // 10px y-strips over [0,640)

// out layout (float32, concatenated in reference return order)
#define OFF_LBL  0
#define OFF_BOX  (BS*NA)                       // 268800
#define OFF_SCR  (BS*NA + BS*NA*4)             // 1344000
#define OFF_POS  (BS*NA + BS*NA*4 + BS*NA*NC)  // 22848000

#define NROWS (BS*NMAX)                        // 3200 gt rows
#define NSC4  (BS*NA*NC/4)                     // 5,376,000 float4 in score region
#define TKBLK 800                              // topk blocks (4 waves = 4 rows)
#define ZBLK2 1024                             // score-zero blocks inside K2
#define NCHUNK 33                              // ceil(NA/256) resolve chunks/batch
#define WPB (NCHUNK*4)                         // 132 resolve waves per batch

// K1 (2 x 1024): block 0 bins anchors into 64 y-strips, emitting strip-sorted
// float4 (x, y, idx-bits, 0) so topk's phase A is ONE 16B coalesced load per
// anchor. Block 1 zeros pa/po/done (the only ws state needing init; the 86MB
// score-zero moved into K2 where it overlaps the latency-stalled topk waves).
__global__ __launch_bounds__(1024) void bin_kernel(
    const float* __restrict__ anchor_points,
    int* __restrict__ strip_off, float4* __restrict__ sAPI,
    unsigned int* __restrict__ pz_base)      // pa,po,done contiguous: 27648 B
{
    int t = threadIdx.x;
    if (blockIdx.x != 0) {
        uint4* pz = (uint4*)pz_base;         // 27648 B = 1728 uint4
        uint4 zz = make_uint4(0u, 0u, 0u, 0u);
        for (int i = t; i < 1728; i += 1024) pz[i] = zz;
        return;
    }

    __shared__ int cnt[NSTRIP];
    __shared__ int cur[NSTRIP];
    if (t < NSTRIP) cnt[t] = 0;
    __syncthreads();
    const float2* ap2 = (const float2*)anchor_points;
    for (int a = t; a < NA; a += 1024) {
        int s = (int)(ap2[a].y * STRIP_INV);
        s = s < 0 ? 0 : (s > NSTRIP - 1 ? NSTRIP - 1 : s);
        atomicAdd(&cnt[s], 1);
    }
    __syncthreads();
    if (t < 64) {   // wave 0: exclusive prefix over 64 strips
        int v = cnt[t];
        int inc = v;
        #pragma unroll
        for (int d = 1; d < 64; d <<= 1) {
            int o = __shfl_up(inc, d, 64);
            if (t >= d) inc += o;
        }
        int excl = inc - v;
        cur[t] = excl; strip_off[t] = excl;
        if (t == 63) strip_off[64] = inc;   // == NA
    }
    __syncthreads();
    for (int a = t; a < NA; a += 1024) {
        float2 p = ap2[a];
        int s = (int)(p.y * STRIP_INV);
        s = s < 0 ? 0 : (s > NSTRIP - 1 ? NSTRIP - 1 : s);
        int pos = atomicAdd(&cur[s], 1);    // order within strip irrelevant
        sAPI[pos] = make_float4(p.x, p.y, __int_as_float(a), 0.f);
    }
}

// K2 (1824 x 256): blocks 0..799 = ONE WAVE PER (b,j) GT ROW (verified 5
// rounds, unchanged). Blocks 800..1823 zero the 86MB score output region —
// streaming BW job overlapped with the latency-bound topk blocks (1824 blocks
// all co-resident: 8/CU x 256 CU = 2048 slots).
__global__ __launch_bounds__(256) void topk_kernel(
    const float* __restrict__ pred_scores,   // BS,NA,NC
    const float* __restrict__ pred_bboxes,   // BS,NA,4
    const int*   __restrict__ gt_labels,     // BS,NMAX,1
    const float* __restrict__ gt_bboxes,     // BS,NMAX,4
    const float* __restrict__ mask_gt,       // BS,NMAX,1
    const int*   __restrict__ strip_off,
    const float4* __restrict__ sAPI,
    unsigned int*   __restrict__ ccount,     // NROWS
    unsigned short* __restrict__ clist,      // NROWS*TOPK
    float* __restrict__ out)
{
    int t = threadIdx.x;
    if (blockIdx.x >= TKBLK) {
        // ---- score-region zero job (86MB, coalesced float4) ----
        int zb = blockIdx.x - TKBLK;
        float4* sz = (float4*)(out + OFF_SCR);
        float4 zf = make_float4(0.f, 0.f, 0.f, 0.f);
        for (int i = zb * 256 + t; i < NSC4; i += ZBLK2 * 256) sz[i] = zf;
        return;
    }

    __shared__ unsigned short aidx[4][WCAP];
    int wave = t >> 6;
    int lane = t & 63;
    int row = blockIdx.x * 4 + wave;         // 800*4 == 3200 rows exactly
    if (mask_gt[row] <= 0.f) {               // wave-uniform, no barriers used
        if (lane == 0) ccount[row] = 0u;
        return;
    }
    int b = row / NMAX;

    const float* gbp = gt_bboxes + (size_t)row * 4;
    float gx1 = gbp[0], gy1 = gbp[1], gx2 = gbp[2], gy2 = gbp[3];
    int lab = gt_labels[row];

    // strip range covering (gy1,gy2): float mul + trunc are monotone, so any
    // anchor passing the exact test lies within [s_lo, s_hi].
    int s_lo = (int)(gy1 * STRIP_INV); s_lo = s_lo < 0 ? 0 : (s_lo > NSTRIP-1 ? NSTRIP-1 : s_lo);
    int s_hi = (int)(gy2 * STRIP_INV); s_hi = s_hi < 0 ? 0 : (s_hi > NSTRIP-1 ? NSTRIP-1 : s_hi);
    int lo = strip_off[s_lo], hi = strip_off[s_hi + 1];

    // Phase A: ballot-compact in-gt anchor indices (wave-private, no atomics)
    int cnt = 0;
    for (int base = lo; base < hi; base += 64) {
        int p = base + lane;
        bool hit = false; int a = 0;
        if (p < hi) {
            float4 ap = sAPI[p];
            a = __float_as_int(ap.z);
            hit = (ap.x - gx1 > EPSF) && (ap.y - gy1 > EPSF) &&
                  (gx2 - ap.x > EPSF) && (gy2 - ap.y > EPSF);
        }
        unsigned long long mb = __ballot(hit);
        if (hit) {
            int my = cnt + __popcll(mb & ((1ULL << lane) - 1ULL));
            if (my < WCAP) aidx[wave][my] = (unsigned short)a;
        }
        cnt += __popcll(mb);   // wave-uniform
    }
    if (cnt > WCAP) cnt = WCAP;

    // Phase B: dense metric pass, per-lane sorted top-13 in registers
    unsigned long long loc[TOPK];
    #pragma unroll
    for (int i = 0; i < TOPK; i++) loc[i] = 0ULL;
    const float4* pb4 = (const float4*)pred_bboxes;
    for (int p = lane; p < cnt; p += 64) {
        int a = aidx[wave][p];
        float4 pb = pb4[b * NA + a];
        float s = pred_scores[((size_t)b * NA + a) * NC + lab];
        float lx = fmaxf(gx1, pb.x), ly = fmaxf(gy1, pb.y);
        float rx = fminf(gx2, pb.z), ry = fminf(gy2, pb.w);
        float w = fmaxf(rx - lx, 0.f), h = fmaxf(ry - ly, 0.f);
        float inter = w * h;
        float aa = (gx2 - gx1) * (gy2 - gy1);
        float ab = (pb.z - pb.x) * (pb.w - pb.y);
        float iou = inter / (aa + ab - inter + EPSF);
        float i2 = iou * iou;
        float m = s * (i2 * i2 * i2);
        if (m > 0.f) {
            // (metric<<32)|(NA-a): u64 order == value desc, index asc (jax tie-break)
            unsigned long long key =
                ((unsigned long long)__float_as_uint(m) << 32) |
                (unsigned int)(NA - a);
            #pragma unroll
            for (int i = 0; i < TOPK; i++) {
                if (key > loc[i]) { unsigned long long tmp = loc[i]; loc[i] = key; key = tmp; }
            }
        }
    }

    // Phase C: 13 extract-max rounds; winner writes its OWN row's list slot
    int picks = TOPK;
    for (int r = 0; r < TOPK; r++) {
        unsigned long long h = loc[0];
        unsigned long long m = h;
        #pragma unroll
        for (int s = 32; s > 0; s >>= 1) {
            unsigned long long o = __shfl_xor(m, s, 64);
            m = o > m ? o : m;
        }
        if (m == 0ULL) { picks = r; break; }   // wave-uniform
        unsigned long long ball = __ballot(h == m);  // keys distinct -> one lane
        if (lane == (int)__builtin_ctzll(ball)) {
            #pragma unroll
            for (int i = 0; i < TOPK - 1; i++) loc[i] = loc[i + 1];
            loc[TOPK - 1] = 0ULL;
            int a = NA - (int)(unsigned int)(m & 0xFFFFFFFFULL);
            clist[row * TOPK + r] = (unsigned short)a;
        }
    }
    if (lane == 0) ccount[row] = (unsigned int)picks;
}

// K3 (33 x BS x 256): resolve (Round-6-verified) + MERGED per-batch scatter
// via the opportunistic last-block pattern (rocPRIM device-reduce idiom):
// each block, after its resolve work, release-fences and bumps done[b]; the
// 33rd block acquire-fences and scatters the batch's positives. No spinning,
// no co-residency assumption (deadlock-free unlike a grid barrier). Cross-
// block data: pa/po via device-scope atomics; wcount/plist plain stores
// bracketed by the threadfence release/acquire pair. Removes K4 + boundary.
__global__ __launch_bounds__(256) void resolve_kernel(
    const float* __restrict__ pred_scores,
    const float* __restrict__ pred_bboxes,
    const int*   __restrict__ gt_labels,
    const float* __restrict__ gt_bboxes,
    const unsigned int*   __restrict__ ccount,
    const unsigned short* __restrict__ clist,
    unsigned int* __restrict__ pa_bits, unsigned int* __restrict__ po_bits,
    unsigned int* __restrict__ done,         // BS counters, 64B-strided
    unsigned int* __restrict__ wcount, uint4* __restrict__ plist,
    float* __restrict__ out)
{
    __shared__ float4 gtb[NMAX];
    __shared__ int    glab[NMAX];
    __shared__ int    ccnt[NMAX];
    __shared__ unsigned int pkl[256];
    __shared__ int lastflag;
    int b = blockIdx.y;
    int t = threadIdx.x;
    int lane = t & 63;
    int lo = blockIdx.x * 256;
    int ai = lo + t;
    bool valid = ai < NA;
    int idx = b * NA + (valid ? ai : 0);

    // issue the coalesced per-anchor box load FIRST (covered by staging+sync)
    float4 pb = ((const float4*)pred_bboxes)[idx];

    if (t < NMAX) {
        gtb[t]  = ((const float4*)gt_bboxes)[b * NMAX + t];
        glab[t] = gt_labels[b * NMAX + t];
        ccnt[t] = (int)ccount[b * NMAX + t];
    }
    pkl[t] = 0u;
    __syncthreads();

    // invert claim lists into this block's anchor window (<=1300 entries)
    for (int e = t; e < NMAX * TOPK; e += 256) {
        int j = e / TOPK, k = e - j * TOPK;
        if (k < ccnt[j]) {
            int a = clist[(b * NMAX + j) * TOPK + k];
            unsigned int w = (unsigned int)(a - lo);
            if (w < 256u) atomicAdd(&pkl[w], (1u << 16) | (unsigned int)j);
        }
    }
    __syncthreads();

    unsigned int pk = valid ? pkl[t] : 0u;
    int js = -1; float iou = 0.f;

    if ((pk >> 16) == 1u) {          // single claim: direct reuse
        js = (int)(pk & 0xFFFFu);
        float4 g = gtb[js];
        float lx = fmaxf(g.x, pb.x), ly = fmaxf(g.y, pb.y);
        float rx = fminf(g.z, pb.z), ry = fminf(g.w, pb.w);
        float w = fmaxf(rx - lx, 0.f), h = fmaxf(ry - ly, 0.f);
        float inter = w * h;
        float aa = (g.z - g.x) * (g.w - g.y);
        float ab = (pb.z - pb.x) * (pb.w - pb.y);
        iou = inter / (aa + ab - inter + EPSF);
    }

    // cooperative multi-claim resolution (wave-uniform loop, ~1 hit/wave avg).
    // Tie-break: key=(iou_bits<<32)|(99-j) -> max picks smallest j on exact
    // ties == jax argmax first-max. IOUs >=0 so bit compare == float compare.
    unsigned long long mm = __ballot((pk >> 16) > 1u);
    while (mm) {
        int src = (int)__builtin_ctzll(mm);
        mm &= mm - 1ULL;
        float qx1 = __shfl(pb.x, src, 64), qy1 = __shfl(pb.y, src, 64);
        float qx2 = __shfl(pb.z, src, 64), qy2 = __shfl(pb.w, src, 64);
        float qab = (qx2 - qx1) * (qy2 - qy1);
        unsigned long long bestkey = 0ULL;
        #pragma unroll
        for (int rep = 0; rep < 2; rep++) {       // j = lane, lane+64 (<100)
            int j = lane + rep * 64;
            if (j < NMAX) {
                float4 g = gtb[j];
                float lx = fmaxf(g.x, qx1), ly = fmaxf(g.y, qy1);
                float rx = fminf(g.z, qx2), ry = fminf(g.w, qy2);
                float w = fmaxf(rx - lx, 0.f), h = fmaxf(ry - ly, 0.f);
                float inter = w * h;
                float aa = (g.z - g.x) * (g.w - g.y);
                float v = inter / (aa + qab - inter + EPSF);
                unsigned long long key =
                    ((unsigned long long)__float_as_uint(v) << 32) |
                    (unsigned int)(NMAX - 1 - j);
                if (key > bestkey) bestkey = key;
            }
        }
        #pragma unroll
        for (int s = 32; s > 0; s >>= 1) {
            unsigned long long o = __shfl_xor(bestkey, s, 64);
            bestkey = o > bestkey ? o : bestkey;
        }
        if (lane == src) {
            js  = NMAX - 1 - (int)(unsigned int)(bestkey & 0xFFFFFFFFULL);
            iou = __uint_as_float((unsigned int)(bestkey >> 32));
        }
    }

    float align = 0.f; int lab = 0;
    if (js >= 0) {
        lab = glab[js];
        float s = pred_scores[(size_t)idx * NC + lab];
        float i2 = iou * iou;
        align = s * (i2 * i2 * i2);   // UNMASKED align metric (reference semantics)
        // non-negative floats: uint bit-pattern compare == float compare;
        // 3200 distinct addresses -> no contention wall
        atomicMax(&pa_bits[b * NMAX + js], __float_as_uint(align));
        atomicMax(&po_bits[b * NMAX + js], __float_as_uint(iou));
    }

    if (valid) {
        bool pos = js >= 0;
        int j0 = pos ? js : 0;   // argmax of all-zero mask_pos -> gt 0
        out[OFF_LBL + idx] = pos ? (float)glab[j0] : (float)NC;
        ((float4*)(out + OFF_BOX))[idx] = gtb[j0];
        out[OFF_POS + idx] = pos ? 1.f : 0.f;
    }

    // per-wave-owned positives segment: plain stores, no atomics (Round-6)
    bool pos = valid && js >= 0;
    unsigned long long mb = __ballot(pos);
    int wid = b * WPB + blockIdx.x * 4 + (t >> 6);
    if (lane == 0) wcount[wid] = (unsigned int)__popcll(mb);
    if (pos) {
        int myoff = __popcll(mb & ((1ULL << lane) - 1ULL));
        plist[wid * 64 + myoff] = make_uint4((unsigned int)idx,
                                             (unsigned int)(b * NMAX + js),
                                             __float_as_uint(align),
                                             (unsigned int)lab);
    }

    // ---- merged scatter: last block of this batch normalizes positives ----
    __threadfence();                 // release: wcount/plist/pa/po visible
    __syncthreads();
    if (t == 0) {
        unsigned int old = atomicAdd(&done[b * 16], 1u);   // 64B-strided ctr
        lastflag = (old == (unsigned int)(NCHUNK - 1));
    }
    __syncthreads();
    if (lastflag) {
        __threadfence();             // acquire: invalidate stale L1/L2 lines
        for (int slot = t; slot < WPB * 64; slot += 256) {
            int w = slot >> 6;                       // wave-uniform per iter
            unsigned int n = wcount[b * WPB + w];
            if ((unsigned int)(slot & 63) < n) {
                uint4 e = plist[(b * WPB + w) * 64 + (slot & 63)];
                float pa = __uint_as_float(pa_bits[e.y]);
                float po = __uint_as_float(po_bits[e.y]);
                out[OFF_SCR + (size_t)e.x * NC + e.w] =
                    __uint_as_float(e.z) * po / (pa + EPSF);
            }
        }
    }
}

extern "C" void kernel_launch(void* const* d_in, const int* in_sizes, int n_in,
                              void* d_out, int out_size, void* d_ws, size_t ws_size,
                              hipStream_t stream) {
    const float* pred_scores   = (const float*)d_in[0];
    const float* pred_bboxes   = (const float*)d_in[1];
    const float* anchor_points = (const float*)d_in[2];
    const int*   gt_labels     = (const int*)d_in[3];
    const float* gt_bboxes     = (const float*)d_in[4];
    const float* mask_gt       = (const float*)d_in[5];

    char* ws = (char*)d_ws;
    // ws layout (no host-side init; ws may be poisoned 0xAA each launch):
    //   [pa 3200 u32][po 3200 u32][done 32x16 u32]  <- zeroed by K1 block 1
    //   [ccount 3200 u32]                 <- fully written by K2
    //   [clist 3200*13 u16]               <- slots < ccount written by K2
    //   [strip_off 65 int (pad)][sAPI 8400 float4]  <- written by K1 block 0
    //   [wcount 4224 u32]                 <- fully written by K3 (plain stores)
    //   [plist 4224*64 uint4]             <- slots < wcount written by K3
    unsigned int*   pa_bits = (unsigned int*)(ws);
    unsigned int*   po_bits = (unsigned int*)(ws + 12800);
    unsigned int*   done    = (unsigned int*)(ws + 25600);   // 2048 B
    unsigned int*   ccount  = (unsigned int*)(ws + 27648);
    unsigned short* clist   = (unsigned short*)(ws + 40448);
    int*    strip_off = (int*)(ws + 123648);             // 40448+83200
    float4* sAPI      = (float4*)(ws + 124160);          // +512 pad
    unsigned int* wcount = (unsigned int*)(ws + 258560); // +8400*16
    uint4*  plist     = (uint4*)(ws + 275456);           // 16B-aligned

    float* out = (float*)d_out;

    // 3 dispatches, 0 memsets, 0 contended atomics:
    bin_kernel<<<2, 1024, 0, stream>>>(
        anchor_points, strip_off, sAPI, pa_bits);

    topk_kernel<<<TKBLK + ZBLK2, 256, 0, stream>>>(
        pred_scores, pred_bboxes, gt_labels, gt_bboxes, mask_gt,
        strip_off, sAPI, ccount, clist, out);

    dim3 rgrid(NCHUNK, BS);
    resolve_kernel<<<rgrid, 256, 0, stream>>>(
        pred_scores, pred_bboxes, gt_labels, gt_bboxes, ccount, clist,
        pa_bits, po_bits, done, wcount, plist, out);
}

// Round 8
// 229.561 us; speedup vs baseline: 1.4829x; 1.4829x over previous
//
#include <hip/hip_runtime.h>

#define BS 32
#define NA 8400
#define NMAX 100
#define NC 80
#define TOPK 13
#define EPSF 1e-9f
#define WCAP 1024    // per-wave candidate cap; true max ~400 (mean ~60)
#define NSTRIP 64
#define STRIP_INV 0.1f   // 10px y-strips over [0,640)

// out layout (float32, concatenated in reference return order)
#define OFF_LBL  0
#define OFF_BOX  (BS*NA)                       // 268800
#define OFF_SCR  (BS*NA + BS*NA*4)             // 1344000
#define OFF_POS  (BS*NA + BS*NA*4 + BS*NA*NC)  // 22848000

#define NROWS (BS*NMAX)                        // 3200 gt rows
#define NSC4  (BS*NA*NC/4)                     // 5,376,000 float4 in score region
#define ZBLK  511                              // zero blocks in K1 (x1024 thr)
#define NCHUNK 33                              // ceil(NA/256) resolve chunks/batch
#define WPB (NCHUNK*4)                         // 132 resolve waves per batch

// K1 (512 x 1024): block 0 bins anchors into 64 y-strips, emitting strip-sorted
// float4 (x, y, idx-bits, 0) so topk's phase A is ONE 16B coalesced load per
// anchor. Blocks 1..511 zero the 86MB score output region (dominant mandatory
// write, overlapped with binning); block 1 also zeros pa/po/done.
__global__ __launch_bounds__(1024) void bin_zero_kernel(
    const float* __restrict__ anchor_points,
    int* __restrict__ strip_off, float4* __restrict__ sAPI,
    unsigned int* __restrict__ pz_base,      // pa,po,done contiguous: 27648 B
    float* __restrict__ out)
{
    int t = threadIdx.x;
    if (blockIdx.x != 0) {
        int zb = blockIdx.x - 1;
        if (zb == 0) {
            uint4* pz = (uint4*)pz_base;     // 27648 B = 1728 uint4
            uint4 zz = make_uint4(0u, 0u, 0u, 0u);
            for (int i = t; i < 1728; i += 1024) pz[i] = zz;
        }
        float4* sz = (float4*)(out + OFF_SCR);
        float4 zf = make_float4(0.f, 0.f, 0.f, 0.f);
        for (int i = zb * 1024 + t; i < NSC4; i += ZBLK * 1024) sz[i] = zf;
        return;
    }

    __shared__ int cnt[NSTRIP];
    __shared__ int cur[NSTRIP];
    if (t < NSTRIP) cnt[t] = 0;
    __syncthreads();
    const float2* ap2 = (const float2*)anchor_points;
    for (int a = t; a < NA; a += 1024) {
        int s = (int)(ap2[a].y * STRIP_INV);
        s = s < 0 ? 0 : (s > NSTRIP - 1 ? NSTRIP - 1 : s);
        atomicAdd(&cnt[s], 1);
    }
    __syncthreads();
    if (t < 64) {   // wave 0: exclusive prefix over 64 strips
        int v = cnt[t];
        int inc = v;
        #pragma unroll
        for (int d = 1; d < 64; d <<= 1) {
            int o = __shfl_up(inc, d, 64);
            if (t >= d) inc += o;
        }
        int excl = inc - v;
        cur[t] = excl; strip_off[t] = excl;
        if (t == 63) strip_off[64] = inc;   // == NA
    }
    __syncthreads();
    for (int a = t; a < NA; a += 1024) {
        float2 p = ap2[a];
        int s = (int)(p.y * STRIP_INV);
        s = s < 0 ? 0 : (s > NSTRIP - 1 ? NSTRIP - 1 : s);
        int pos = atomicAdd(&cur[s], 1);    // order within strip irrelevant
        sAPI[pos] = make_float4(p.x, p.y, __int_as_float(a), 0.f);
    }
}

// K2 (800 x 256): ONE WAVE PER (b,j) GT ROW — verified 6 rounds, unchanged.
__global__ __launch_bounds__(256) void topk_kernel(
    const float* __restrict__ pred_scores,   // BS,NA,NC
    const float* __restrict__ pred_bboxes,   // BS,NA,4
    const int*   __restrict__ gt_labels,     // BS,NMAX,1
    const float* __restrict__ gt_bboxes,     // BS,NMAX,4
    const float* __restrict__ mask_gt,       // BS,NMAX,1
    const int*   __restrict__ strip_off,
    const float4* __restrict__ sAPI,
    unsigned int*   __restrict__ ccount,     // NROWS
    unsigned short* __restrict__ clist)      // NROWS*TOPK
{
    __shared__ unsigned short aidx[4][WCAP];
    int t = threadIdx.x;
    int wave = t >> 6;
    int lane = t & 63;
    int row = blockIdx.x * 4 + wave;         // 800*4 == 3200 rows exactly
    if (mask_gt[row] <= 0.f) {               // wave-uniform, no barriers used
        if (lane == 0) ccount[row] = 0u;
        return;
    }
    int b = row / NMAX;

    const float* gbp = gt_bboxes + (size_t)row * 4;
    float gx1 = gbp[0], gy1 = gbp[1], gx2 = gbp[2], gy2 = gbp[3];
    int lab = gt_labels[row];

    // strip range covering (gy1,gy2): float mul + trunc are monotone, so any
    // anchor passing the exact test lies within [s_lo, s_hi].
    int s_lo = (int)(gy1 * STRIP_INV); s_lo = s_lo < 0 ? 0 : (s_lo > NSTRIP-1 ? NSTRIP-1 : s_lo);
    int s_hi = (int)(gy2 * STRIP_INV); s_hi = s_hi < 0 ? 0 : (s_hi > NSTRIP-1 ? NSTRIP-1 : s_hi);
    int lo = strip_off[s_lo], hi = strip_off[s_hi + 1];

    // Phase A: ballot-compact in-gt anchor indices (wave-private, no atomics)
    int cnt = 0;
    for (int base = lo; base < hi; base += 64) {
        int p = base + lane;
        bool hit = false; int a = 0;
        if (p < hi) {
            float4 ap = sAPI[p];
            a = __float_as_int(ap.z);
            hit = (ap.x - gx1 > EPSF) && (ap.y - gy1 > EPSF) &&
                  (gx2 - ap.x > EPSF) && (gy2 - ap.y > EPSF);
        }
        unsigned long long mb = __ballot(hit);
        if (hit) {
            int my = cnt + __popcll(mb & ((1ULL << lane) - 1ULL));
            if (my < WCAP) aidx[wave][my] = (unsigned short)a;
        }
        cnt += __popcll(mb);   // wave-uniform
    }
    if (cnt > WCAP) cnt = WCAP;

    // Phase B: dense metric pass, per-lane sorted top-13 in registers
    unsigned long long loc[TOPK];
    #pragma unroll
    for (int i = 0; i < TOPK; i++) loc[i] = 0ULL;
    const float4* pb4 = (const float4*)pred_bboxes;
    for (int p = lane; p < cnt; p += 64) {
        int a = aidx[wave][p];
        float4 pb = pb4[b * NA + a];
        float s = pred_scores[((size_t)b * NA + a) * NC + lab];
        float lx = fmaxf(gx1, pb.x), ly = fmaxf(gy1, pb.y);
        float rx = fminf(gx2, pb.z), ry = fminf(gy2, pb.w);
        float w = fmaxf(rx - lx, 0.f), h = fmaxf(ry - ly, 0.f);
        float inter = w * h;
        float aa = (gx2 - gx1) * (gy2 - gy1);
        float ab = (pb.z - pb.x) * (pb.w - pb.y);
        float iou = inter / (aa + ab - inter + EPSF);
        float i2 = iou * iou;
        float m = s * (i2 * i2 * i2);
        if (m > 0.f) {
            // (metric<<32)|(NA-a): u64 order == value desc, index asc (jax tie-break)
            unsigned long long key =
                ((unsigned long long)__float_as_uint(m) << 32) |
                (unsigned int)(NA - a);
            #pragma unroll
            for (int i = 0; i < TOPK; i++) {
                if (key > loc[i]) { unsigned long long tmp = loc[i]; loc[i] = key; key = tmp; }
            }
        }
    }

    // Phase C: 13 extract-max rounds; winner writes its OWN row's list slot
    int picks = TOPK;
    for (int r = 0; r < TOPK; r++) {
        unsigned long long h = loc[0];
        unsigned long long m = h;
        #pragma unroll
        for (int s = 32; s > 0; s >>= 1) {
            unsigned long long o = __shfl_xor(m, s, 64);
            m = o > m ? o : m;
        }
        if (m == 0ULL) { picks = r; break; }   // wave-uniform
        unsigned long long ball = __ballot(h == m);  // keys distinct -> one lane
        if (lane == (int)__builtin_ctzll(ball)) {
            #pragma unroll
            for (int i = 0; i < TOPK - 1; i++) loc[i] = loc[i + 1];
            loc[TOPK - 1] = 0ULL;
            int a = NA - (int)(unsigned int)(m & 0xFFFFFFFFULL);
            clist[row * TOPK + r] = (unsigned short)a;
        }
    }
    if (lane == 0) ccount[row] = (unsigned int)picks;
}

// K3 (33 x BS x 256): resolve (Round-6-verified) + merged per-batch scatter
// via the last-block pattern — this time with FENCE-FREE transport. Round-7's
// __threadfence (= s_waitcnt + buffer_wbl2, a full dirty-L2 writeback) x4224
// waves was the 171us disaster. Here ALL cross-block data moves through
// device-scope RELAXED atomics (coherence-point ops, no cache flush):
//   wcount/plist: __hip_atomic_store / __hip_atomic_load (AGENT, relaxed)
//   pa/po:        atomicMax writes (already device scope) + atomic loads
// Release ordering per wave = one `s_waitcnt vmcnt(0)` (waits for this
// wave's own stores to reach the coherence point; NOT an L2 flush), then
// __syncthreads, then the done[b] relaxed fetch_add. Reader (old==32) needs
// no acquire fence: relaxed atomic loads read the coherence point directly.
__global__ __launch_bounds__(256) void resolve_kernel(
    const float* __restrict__ pred_scores,
    const float* __restrict__ pred_bboxes,
    const int*   __restrict__ gt_labels,
    const float* __restrict__ gt_bboxes,
    const unsigned int*   __restrict__ ccount,
    const unsigned short* __restrict__ clist,
    unsigned int* __restrict__ pa_bits, unsigned int* __restrict__ po_bits,
    unsigned int* __restrict__ done,         // BS counters, 64B-strided
    unsigned int* __restrict__ wcount, unsigned long long* __restrict__ plist,
    float* __restrict__ out)
{
    __shared__ float4 gtb[NMAX];
    __shared__ int    glab[NMAX];
    __shared__ int    ccnt[NMAX];
    __shared__ unsigned int pkl[256];
    __shared__ int lastflag;
    int b = blockIdx.y;
    int t = threadIdx.x;
    int lane = t & 63;
    int lo = blockIdx.x * 256;
    int ai = lo + t;
    bool valid = ai < NA;
    int idx = b * NA + (valid ? ai : 0);

    // issue the coalesced per-anchor box load FIRST (covered by staging+sync)
    float4 pb = ((const float4*)pred_bboxes)[idx];

    if (t < NMAX) {
        gtb[t]  = ((const float4*)gt_bboxes)[b * NMAX + t];
        glab[t] = gt_labels[b * NMAX + t];
        ccnt[t] = (int)ccount[b * NMAX + t];
    }
    pkl[t] = 0u;
    __syncthreads();

    // invert claim lists into this block's anchor window (<=1300 entries)
    for (int e = t; e < NMAX * TOPK; e += 256) {
        int j = e / TOPK, k = e - j * TOPK;
        if (k < ccnt[j]) {
            int a = clist[(b * NMAX + j) * TOPK + k];
            unsigned int w = (unsigned int)(a - lo);
            if (w < 256u) atomicAdd(&pkl[w], (1u << 16) | (unsigned int)j);
        }
    }
    __syncthreads();

    unsigned int pk = valid ? pkl[t] : 0u;
    int js = -1; float iou = 0.f;

    if ((pk >> 16) == 1u) {          // single claim: direct reuse
        js = (int)(pk & 0xFFFFu);
        float4 g = gtb[js];
        float lx = fmaxf(g.x, pb.x), ly = fmaxf(g.y, pb.y);
        float rx = fminf(g.z, pb.z), ry = fminf(g.w, pb.w);
        float w = fmaxf(rx - lx, 0.f), h = fmaxf(ry - ly, 0.f);
        float inter = w * h;
        float aa = (g.z - g.x) * (g.w - g.y);
        float ab = (pb.z - pb.x) * (pb.w - pb.y);
        iou = inter / (aa + ab - inter + EPSF);
    }

    // cooperative multi-claim resolution (wave-uniform loop, ~1 hit/wave avg).
    // Tie-break: key=(iou_bits<<32)|(99-j) -> max picks smallest j on exact
    // ties == jax argmax first-max. IOUs >=0 so bit compare == float compare.
    unsigned long long mm = __ballot((pk >> 16) > 1u);
    while (mm) {
        int src = (int)__builtin_ctzll(mm);
        mm &= mm - 1ULL;
        float qx1 = __shfl(pb.x, src, 64), qy1 = __shfl(pb.y, src, 64);
        float qx2 = __shfl(pb.z, src, 64), qy2 = __shfl(pb.w, src, 64);
        float qab = (qx2 - qx1) * (qy2 - qy1);
        unsigned long long bestkey = 0ULL;
        #pragma unroll
        for (int rep = 0; rep < 2; rep++) {       // j = lane, lane+64 (<100)
            int j = lane + rep * 64;
            if (j < NMAX) {
                float4 g = gtb[j];
                float lx = fmaxf(g.x, qx1), ly = fmaxf(g.y, qy1);
                float rx = fminf(g.z, qx2), ry = fminf(g.w, qy2);
                float w = fmaxf(rx - lx, 0.f), h = fmaxf(ry - ly, 0.f);
                float inter = w * h;
                float aa = (g.z - g.x) * (g.w - g.y);
                float v = inter / (aa + qab - inter + EPSF);
                unsigned long long key =
                    ((unsigned long long)__float_as_uint(v) << 32) |
                    (unsigned int)(NMAX - 1 - j);
                if (key > bestkey) bestkey = key;
            }
        }
        #pragma unroll
        for (int s = 32; s > 0; s >>= 1) {
            unsigned long long o = __shfl_xor(bestkey, s, 64);
            bestkey = o > bestkey ? o : bestkey;
        }
        if (lane == src) {
            js  = NMAX - 1 - (int)(unsigned int)(bestkey & 0xFFFFFFFFULL);
            iou = __uint_as_float((unsigned int)(bestkey >> 32));
        }
    }

    float align = 0.f; int lab = 0;
    if (js >= 0) {
        lab = glab[js];
        float s = pred_scores[(size_t)idx * NC + lab];
        float i2 = iou * iou;
        align = s * (i2 * i2 * i2);   // UNMASKED align metric (reference semantics)
        // non-negative floats: uint bit-pattern compare == float compare;
        // 3200 distinct addresses -> no contention wall
        atomicMax(&pa_bits[b * NMAX + js], __float_as_uint(align));
        atomicMax(&po_bits[b * NMAX + js], __float_as_uint(iou));
    }

    if (valid) {
        bool pos = js >= 0;
        int j0 = pos ? js : 0;   // argmax of all-zero mask_pos -> gt 0
        out[OFF_LBL + idx] = pos ? (float)glab[j0] : (float)NC;
        ((float4*)(out + OFF_BOX))[idx] = gtb[j0];
        out[OFF_POS + idx] = pos ? 1.f : 0.f;
    }

    // per-wave-owned positives segment, written as relaxed device-scope
    // atomic stores (coherence-point visible; no fence needed)
    bool pos = valid && js >= 0;
    unsigned long long mb = __ballot(pos);
    int wid = b * WPB + blockIdx.x * 4 + (t >> 6);
    if (lane == 0)
        __hip_atomic_store(&wcount[wid], (unsigned int)__popcll(mb),
                           __ATOMIC_RELAXED, __HIP_MEMORY_SCOPE_AGENT);
    if (pos) {
        int myoff = __popcll(mb & ((1ULL << lane) - 1ULL));
        unsigned long long e0 = (unsigned long long)(unsigned int)idx |
                                ((unsigned long long)(unsigned int)(b * NMAX + js) << 32);
        unsigned long long e1 = (unsigned long long)__float_as_uint(align) |
                                ((unsigned long long)(unsigned int)lab << 32);
        __hip_atomic_store(&plist[(wid * 64 + myoff) * 2 + 0], e0,
                           __ATOMIC_RELAXED, __HIP_MEMORY_SCOPE_AGENT);
        __hip_atomic_store(&plist[(wid * 64 + myoff) * 2 + 1], e1,
                           __ATOMIC_RELAXED, __HIP_MEMORY_SCOPE_AGENT);
    }

    // ---- release: each wave drains ITS OWN vmem (cheap), then count ----
    asm volatile("s_waitcnt vmcnt(0)" ::: "memory");
    __syncthreads();
    if (t == 0) {
        unsigned int old = __hip_atomic_fetch_add(&done[b * 16], 1u,
                               __ATOMIC_RELAXED, __HIP_MEMORY_SCOPE_AGENT);
        lastflag = (old == (unsigned int)(NCHUNK - 1));
    }
    __syncthreads();

    // ---- last block of this batch scatters its ~1000 positives ----
    if (lastflag) {
        for (int slot = t; slot < WPB * 64; slot += 256) {
            int w = slot >> 6;                       // wave-uniform per iter
            unsigned int n = __hip_atomic_load(&wcount[b * WPB + w],
                                 __ATOMIC_RELAXED, __HIP_MEMORY_SCOPE_AGENT);
            if ((unsigned int)(slot & 63) < n) {
                unsigned long long e0 = __hip_atomic_load(
                    &plist[((b * WPB + w) * 64 + (slot & 63)) * 2 + 0],
                    __ATOMIC_RELAXED, __HIP_MEMORY_SCOPE_AGENT);
                unsigned long long e1 = __hip_atomic_load(
                    &plist[((b * WPB + w) * 64 + (slot & 63)) * 2 + 1],
                    __ATOMIC_RELAXED, __HIP_MEMORY_SCOPE_AGENT);
                unsigned int eidx = (unsigned int)e0;
                unsigned int egt  = (unsigned int)(e0 >> 32);
                float ealign = __uint_as_float((unsigned int)e1);
                unsigned int elab = (unsigned int)(e1 >> 32);
                unsigned int pab = __hip_atomic_load(&pa_bits[egt],
                                     __ATOMIC_RELAXED, __HIP_MEMORY_SCOPE_AGENT);
                unsigned int pob = __hip_atomic_load(&po_bits[egt],
                                     __ATOMIC_RELAXED, __HIP_MEMORY_SCOPE_AGENT);
                out[OFF_SCR + (size_t)eidx * NC + elab] =
                    ealign * __uint_as_float(pob) / (__uint_as_float(pab) + EPSF);
            }
        }
    }
}

extern "C" void kernel_launch(void* const* d_in, const int* in_sizes, int n_in,
                              void* d_out, int out_size, void* d_ws, size_t ws_size,
                              hipStream_t stream) {
    const float* pred_scores   = (const float*)d_in[0];
    const float* pred_bboxes   = (const float*)d_in[1];
    const float* anchor_points = (const float*)d_in[2];
    const int*   gt_labels     = (const int*)d_in[3];
    const float* gt_bboxes     = (const float*)d_in[4];
    const float* mask_gt       = (const float*)d_in[5];

    char* ws = (char*)d_ws;
    // ws layout (no host-side init; ws may be poisoned 0xAA each launch):
    //   [pa 3200 u32][po 3200 u32][done 32x16 u32]  <- zeroed by K1 block 1
    //   [ccount 3200 u32]                 <- fully written by K2
    //   [clist 3200*13 u16]               <- slots < ccount written by K2
    //   [strip_off 65 int (pad)][sAPI 8400 float4]  <- written by K1 block 0
    //   [wcount 4224 u32]                 <- fully written by K3 (atomic stores)
    //   [plist 4224*64 x 16B]             <- slots < wcount written by K3
    unsigned int*   pa_bits = (unsigned int*)(ws);
    unsigned int*   po_bits = (unsigned int*)(ws + 12800);
    unsigned int*   done    = (unsigned int*)(ws + 25600);   // 2048 B
    unsigned int*   ccount  = (unsigned int*)(ws + 27648);
    unsigned short* clist   = (unsigned short*)(ws + 40448);
    int*    strip_off = (int*)(ws + 123648);             // 40448+83200
    float4* sAPI      = (float4*)(ws + 124160);          // +512 pad
    unsigned int* wcount = (unsigned int*)(ws + 258560); // +8400*16
    unsigned long long* plist = (unsigned long long*)(ws + 275456); // 16B-aligned

    float* out = (float*)d_out;

    // 3 dispatches, 0 memsets, 0 contended atomics, 0 L2-flush fences:
    bin_zero_kernel<<<1 + ZBLK, 1024, 0, stream>>>(
        anchor_points, strip_off, sAPI, pa_bits, out);

    topk_kernel<<<NROWS / 4, 256, 0, stream>>>(
        pred_scores, pred_bboxes, gt_labels, gt_bboxes, mask_gt,
        strip_off, sAPI, ccount, clist);

    dim3 rgrid(NCHUNK, BS);
    resolve_kernel<<<rgrid, 256, 0, stream>>>(
        pred_scores, pred_bboxes, gt_labels, gt_bboxes, ccount, clist,
        pa_bits, po_bits, done, wcount, plist, out);
}

// Round 9
// 198.326 us; speedup vs baseline: 1.7164x; 1.1575x over previous
//
#include <hip/hip_runtime.h>

#define BS 32
#define NA 8400
#define NMAX 100
#define NC 80
#define TOPK 13
#define EPSF 1e-9f
#define WCAP 1024    // per-wave candidate cap; true max ~400 (mean ~60)
#define NSTRIP 64
#define STRIP_INV 0.1f   // 10px y-strips over [0,640)

// out layout (float32, concatenated in reference return order)
#define OFF_LBL  0
#define OFF_BOX  (BS*NA)                       // 268800
#define OFF_SCR  (BS*NA + BS*NA*4)             // 1344000
#define OFF_POS  (BS*NA + BS*NA*4 + BS*NA*NC)  // 22848000

#define NROWS (BS*NMAX)                        // 3200 gt rows
#define NSC4  (BS*NA*NC/4)                     // 5,376,000 float4 in score region
#define TKBLK 800                              // topk blocks (4 waves = 4 rows)
#define ZBLK2 1024                             // score-zero blocks inside K2
#define NCHUNK 33                              // ceil(NA/256) resolve chunks/batch
#define NWID  (BS*NCHUNK*4)                    // 4224 resolve waves

// K1 (2 x 1024): block 0 bins anchors into 64 y-strips, emitting strip-sorted
// float4 (x, y, idx-bits, 0) so topk's phase A is ONE 16B coalesced load per
// anchor. Block 1 zeros pa/po (the only ws state needing init). The 86MB
// score-zero lives in K2 where it overlaps the latency-stalled topk waves
// (R7-verified split; R7's failure was exclusively K3's threadfence).
__global__ __launch_bounds__(1024) void bin_kernel(
    const float* __restrict__ anchor_points,
    int* __restrict__ strip_off, float4* __restrict__ sAPI,
    unsigned int* __restrict__ pz_base)      // pa,po contiguous: 25600 B
{
    int t = threadIdx.x;
    if (blockIdx.x != 0) {
        uint4* pz = (uint4*)pz_base;         // 25600 B = 1600 uint4
        uint4 zz = make_uint4(0u, 0u, 0u, 0u);
        for (int i = t; i < 1600; i += 1024) pz[i] = zz;
        return;
    }

    __shared__ int cnt[NSTRIP];
    __shared__ int cur[NSTRIP];
    if (t < NSTRIP) cnt[t] = 0;
    __syncthreads();
    const float2* ap2 = (const float2*)anchor_points;
    for (int a = t; a < NA; a += 1024) {
        int s = (int)(ap2[a].y * STRIP_INV);
        s = s < 0 ? 0 : (s > NSTRIP - 1 ? NSTRIP - 1 : s);
        atomicAdd(&cnt[s], 1);
    }
    __syncthreads();
    if (t < 64) {   // wave 0: exclusive prefix over 64 strips
        int v = cnt[t];
        int inc = v;
        #pragma unroll
        for (int d = 1; d < 64; d <<= 1) {
            int o = __shfl_up(inc, d, 64);
            if (t >= d) inc += o;
        }
        int excl = inc - v;
        cur[t] = excl; strip_off[t] = excl;
        if (t == 63) strip_off[64] = inc;   // == NA
    }
    __syncthreads();
    for (int a = t; a < NA; a += 1024) {
        float2 p = ap2[a];
        int s = (int)(p.y * STRIP_INV);
        s = s < 0 ? 0 : (s > NSTRIP - 1 ? NSTRIP - 1 : s);
        int pos = atomicAdd(&cur[s], 1);    // order within strip irrelevant
        sAPI[pos] = make_float4(p.x, p.y, __int_as_float(a), 0.f);
    }
}

// K2 (1824 x 256): blocks 0..799 = ONE WAVE PER (b,j) GT ROW (verified 6
// rounds, unchanged). Blocks 800..1823 zero the 86MB score output region —
// streaming-BW job overlapped with the latency-bound topk waves (1824 blocks
// x 4 waves ~= 7.1 waves/SIMD: co-resident).
__global__ __launch_bounds__(256) void topk_kernel(
    const float* __restrict__ pred_scores,   // BS,NA,NC
    const float* __restrict__ pred_bboxes,   // BS,NA,4
    const int*   __restrict__ gt_labels,     // BS,NMAX,1
    const float* __restrict__ gt_bboxes,     // BS,NMAX,4
    const float* __restrict__ mask_gt,       // BS,NMAX,1
    const int*   __restrict__ strip_off,
    const float4* __restrict__ sAPI,
    unsigned int*   __restrict__ ccount,     // NROWS
    unsigned short* __restrict__ clist,      // NROWS*TOPK
    float* __restrict__ out)
{
    int t = threadIdx.x;
    if (blockIdx.x >= TKBLK) {
        // ---- score-region zero job (86MB, coalesced float4) ----
        int zb = blockIdx.x - TKBLK;
        float4* sz = (float4*)(out + OFF_SCR);
        float4 zf = make_float4(0.f, 0.f, 0.f, 0.f);
        for (int i = zb * 256 + t; i < NSC4; i += ZBLK2 * 256) sz[i] = zf;
        return;
    }

    __shared__ unsigned short aidx[4][WCAP];
    int wave = t >> 6;
    int lane = t & 63;
    int row = blockIdx.x * 4 + wave;         // 800*4 == 3200 rows exactly
    if (mask_gt[row] <= 0.f) {               // wave-uniform, no barriers used
        if (lane == 0) ccount[row] = 0u;
        return;
    }
    int b = row / NMAX;

    const float* gbp = gt_bboxes + (size_t)row * 4;
    float gx1 = gbp[0], gy1 = gbp[1], gx2 = gbp[2], gy2 = gbp[3];
    int lab = gt_labels[row];

    // strip range covering (gy1,gy2): float mul + trunc are monotone, so any
    // anchor passing the exact test lies within [s_lo, s_hi].
    int s_lo = (int)(gy1 * STRIP_INV); s_lo = s_lo < 0 ? 0 : (s_lo > NSTRIP-1 ? NSTRIP-1 : s_lo);
    int s_hi = (int)(gy2 * STRIP_INV); s_hi = s_hi < 0 ? 0 : (s_hi > NSTRIP-1 ? NSTRIP-1 : s_hi);
    int lo = strip_off[s_lo], hi = strip_off[s_hi + 1];

    // Phase A: ballot-compact in-gt anchor indices (wave-private, no atomics)
    int cnt = 0;
    for (int base = lo; base < hi; base += 64) {
        int p = base + lane;
        bool hit = false; int a = 0;
        if (p < hi) {
            float4 ap = sAPI[p];
            a = __float_as_int(ap.z);
            hit = (ap.x - gx1 > EPSF) && (ap.y - gy1 > EPSF) &&
                  (gx2 - ap.x > EPSF) && (gy2 - ap.y > EPSF);
        }
        unsigned long long mb = __ballot(hit);
        if (hit) {
            int my = cnt + __popcll(mb & ((1ULL << lane) - 1ULL));
            if (my < WCAP) aidx[wave][my] = (unsigned short)a;
        }
        cnt += __popcll(mb);   // wave-uniform
    }
    if (cnt > WCAP) cnt = WCAP;

    // Phase B: dense metric pass, per-lane sorted top-13 in registers
    unsigned long long loc[TOPK];
    #pragma unroll
    for (int i = 0; i < TOPK; i++) loc[i] = 0ULL;
    const float4* pb4 = (const float4*)pred_bboxes;
    for (int p = lane; p < cnt; p += 64) {
        int a = aidx[wave][p];
        float4 pb = pb4[b * NA + a];
        float s = pred_scores[((size_t)b * NA + a) * NC + lab];
        float lx = fmaxf(gx1, pb.x), ly = fmaxf(gy1, pb.y);
        float rx = fminf(gx2, pb.z), ry = fminf(gy2, pb.w);
        float w = fmaxf(rx - lx, 0.f), h = fmaxf(ry - ly, 0.f);
        float inter = w * h;
        float aa = (gx2 - gx1) * (gy2 - gy1);
        float ab = (pb.z - pb.x) * (pb.w - pb.y);
        float iou = inter / (aa + ab - inter + EPSF);
        float i2 = iou * iou;
        float m = s * (i2 * i2 * i2);
        if (m > 0.f) {
            // (metric<<32)|(NA-a): u64 order == value desc, index asc (jax tie-break)
            unsigned long long key =
                ((unsigned long long)__float_as_uint(m) << 32) |
                (unsigned int)(NA - a);
            #pragma unroll
            for (int i = 0; i < TOPK; i++) {
                if (key > loc[i]) { unsigned long long tmp = loc[i]; loc[i] = key; key = tmp; }
            }
        }
    }

    // Phase C: 13 extract-max rounds; winner writes its OWN row's list slot
    int picks = TOPK;
    for (int r = 0; r < TOPK; r++) {
        unsigned long long h = loc[0];
        unsigned long long m = h;
        #pragma unroll
        for (int s = 32; s > 0; s >>= 1) {
            unsigned long long o = __shfl_xor(m, s, 64);
            m = o > m ? o : m;
        }
        if (m == 0ULL) { picks = r; break; }   // wave-uniform
        unsigned long long ball = __ballot(h == m);  // keys distinct -> one lane
        if (lane == (int)__builtin_ctzll(ball)) {
            #pragma unroll
            for (int i = 0; i < TOPK - 1; i++) loc[i] = loc[i + 1];
            loc[TOPK - 1] = 0ULL;
            int a = NA - (int)(unsigned int)(m & 0xFFFFFFFFULL);
            clist[row * TOPK + r] = (unsigned short)a;
        }
    }
    if (lane == 0) ccount[row] = (unsigned int)picks;
}

// K3 (33 x BS x 256): Round-6-verified resolve, verbatim. Per-wave-owned
// positives segments (plain stores, zero contended atomics). No cross-block
// sync of any kind — R7 (threadfence) and R8 (relaxed-atomic transport) both
// proved in-kernel sync costs more than the dispatch boundary it replaces.
__global__ __launch_bounds__(256) void resolve_kernel(
    const float* __restrict__ pred_scores,
    const float* __restrict__ pred_bboxes,
    const int*   __restrict__ gt_labels,
    const float* __restrict__ gt_bboxes,
    const unsigned int*   __restrict__ ccount,
    const unsigned short* __restrict__ clist,
    unsigned int* __restrict__ pa_bits, unsigned int* __restrict__ po_bits,
    unsigned int* __restrict__ wcount, uint4* __restrict__ plist,
    float* __restrict__ out)
{
    __shared__ float4 gtb[NMAX];
    __shared__ int    glab[NMAX];
    __shared__ int    ccnt[NMAX];
    __shared__ unsigned int pkl[256];
    int b = blockIdx.y;
    int t = threadIdx.x;
    int lane = t & 63;
    int lo = blockIdx.x * 256;
    int ai = lo + t;
    bool valid = ai < NA;
    int idx = b * NA + (valid ? ai : 0);

    // issue the coalesced per-anchor box load FIRST (covered by staging+sync)
    float4 pb = ((const float4*)pred_bboxes)[idx];

    if (t < NMAX) {
        gtb[t]  = ((const float4*)gt_bboxes)[b * NMAX + t];
        glab[t] = gt_labels[b * NMAX + t];
        ccnt[t] = (int)ccount[b * NMAX + t];
    }
    pkl[t] = 0u;
    __syncthreads();

    // invert claim lists into this block's anchor window (<=1300 entries)
    for (int e = t; e < NMAX * TOPK; e += 256) {
        int j = e / TOPK, k = e - j * TOPK;
        if (k < ccnt[j]) {
            int a = clist[(b * NMAX + j) * TOPK + k];
            unsigned int w = (unsigned int)(a - lo);
            if (w < 256u) atomicAdd(&pkl[w], (1u << 16) | (unsigned int)j);
        }
    }
    __syncthreads();

    unsigned int pk = valid ? pkl[t] : 0u;
    int js = -1; float iou = 0.f;

    if ((pk >> 16) == 1u) {          // single claim: direct reuse
        js = (int)(pk & 0xFFFFu);
        float4 g = gtb[js];
        float lx = fmaxf(g.x, pb.x), ly = fmaxf(g.y, pb.y);
        float rx = fminf(g.z, pb.z), ry = fminf(g.w, pb.w);
        float w = fmaxf(rx - lx, 0.f), h = fmaxf(ry - ly, 0.f);
        float inter = w * h;
        float aa = (g.z - g.x) * (g.w - g.y);
        float ab = (pb.z - pb.x) * (pb.w - pb.y);
        iou = inter / (aa + ab - inter + EPSF);
    }

    // cooperative multi-claim resolution (wave-uniform loop, ~1 hit/wave avg).
    // Tie-break: key=(iou_bits<<32)|(99-j) -> max picks smallest j on exact
    // ties == jax argmax first-max. IOUs >=0 so bit compare == float compare.
    unsigned long long mm = __ballot((pk >> 16) > 1u);
    while (mm) {
        int src = (int)__builtin_ctzll(mm);
        mm &= mm - 1ULL;
        float qx1 = __shfl(pb.x, src, 64), qy1 = __shfl(pb.y, src, 64);
        float qx2 = __shfl(pb.z, src, 64), qy2 = __shfl(pb.w, src, 64);
        float qab = (qx2 - qx1) * (qy2 - qy1);
        unsigned long long bestkey = 0ULL;
        #pragma unroll
        for (int rep = 0; rep < 2; rep++) {       // j = lane, lane+64 (<100)
            int j = lane + rep * 64;
            if (j < NMAX) {
                float4 g = gtb[j];
                float lx = fmaxf(g.x, qx1), ly = fmaxf(g.y, qy1);
                float rx = fminf(g.z, qx2), ry = fminf(g.w, qy2);
                float w = fmaxf(rx - lx, 0.f), h = fmaxf(ry - ly, 0.f);
                float inter = w * h;
                float aa = (g.z - g.x) * (g.w - g.y);
                float v = inter / (aa + qab - inter + EPSF);
                unsigned long long key =
                    ((unsigned long long)__float_as_uint(v) << 32) |
                    (unsigned int)(NMAX - 1 - j);
                if (key > bestkey) bestkey = key;
            }
        }
        #pragma unroll
        for (int s = 32; s > 0; s >>= 1) {
            unsigned long long o = __shfl_xor(bestkey, s, 64);
            bestkey = o > bestkey ? o : bestkey;
        }
        if (lane == src) {
            js  = NMAX - 1 - (int)(unsigned int)(bestkey & 0xFFFFFFFFULL);
            iou = __uint_as_float((unsigned int)(bestkey >> 32));
        }
    }

    float align = 0.f; int lab = 0;
    if (js >= 0) {
        lab = glab[js];
        float s = pred_scores[(size_t)idx * NC + lab];
        float i2 = iou * iou;
        align = s * (i2 * i2 * i2);   // UNMASKED align metric (reference semantics)
        // non-negative floats: uint bit-pattern compare == float compare;
        // 3200 distinct addresses -> no contention wall
        atomicMax(&pa_bits[b * NMAX + js], __float_as_uint(align));
        atomicMax(&po_bits[b * NMAX + js], __float_as_uint(iou));
    }

    if (valid) {
        bool pos = js >= 0;
        int j0 = pos ? js : 0;   // argmax of all-zero mask_pos -> gt 0
        out[OFF_LBL + idx] = pos ? (float)glab[j0] : (float)NC;
        ((float4*)(out + OFF_BOX))[idx] = gtb[j0];
        out[OFF_POS + idx] = pos ? 1.f : 0.f;
    }

    // per-wave-owned positives segment: plain stores, no atomics (Round-6)
    bool pos = valid && js >= 0;
    unsigned long long mb = __ballot(pos);
    int wid = (b * NCHUNK + blockIdx.x) * 4 + (t >> 6);
    if (lane == 0) wcount[wid] = (unsigned int)__popcll(mb);
    if (pos) {
        int myoff = __popcll(mb & ((1ULL << lane) - 1ULL));
        plist[wid * 64 + myoff] = make_uint4((unsigned int)idx,
                                             (unsigned int)(b * NMAX + js),
                                             __float_as_uint(align),
                                             (unsigned int)lab);
    }
}

// K4 (1056 x 256): one wave per plist segment, lane i handles slot i.
// wcount load is wave-uniform; ~30K scattered 4B stores into the pre-zeroed
// score region. pa/po complete after K3's dispatch boundary.
__global__ __launch_bounds__(256) void scatter_kernel(
    const unsigned int* __restrict__ wcount, const uint4* __restrict__ plist,
    const unsigned int* __restrict__ pa_bits, const unsigned int* __restrict__ po_bits,
    float* __restrict__ out)
{
    int wid = blockIdx.x * 4 + (threadIdx.x >> 6);
    int lane = threadIdx.x & 63;
    unsigned int n = wcount[wid];
    if ((unsigned int)lane < n) {
        uint4 e = plist[wid * 64 + lane];
        float pa = __uint_as_float(pa_bits[e.y]);
        float po = __uint_as_float(po_bits[e.y]);
        out[OFF_SCR + (size_t)e.x * NC + e.w] = __uint_as_float(e.z) * po / (pa + EPSF);
    }
}

extern "C" void kernel_launch(void* const* d_in, const int* in_sizes, int n_in,
                              void* d_out, int out_size, void* d_ws, size_t ws_size,
                              hipStream_t stream) {
    const float* pred_scores   = (const float*)d_in[0];
    const float* pred_bboxes   = (const float*)d_in[1];
    const float* anchor_points = (const float*)d_in[2];
    const int*   gt_labels     = (const int*)d_in[3];
    const float* gt_bboxes     = (const float*)d_in[4];
    const float* mask_gt       = (const float*)d_in[5];

    char* ws = (char*)d_ws;
    // ws layout (no host-side init; ws may be poisoned 0xAA each launch):
    //   [pa 3200 u32][po 3200 u32]        <- zeroed by K1 block 1
    //   [ccount 3200 u32]                 <- fully written by K2
    //   [clist 3200*13 u16]               <- slots < ccount written by K2
    //   [strip_off 65 int (pad)][sAPI 8400 float4]  <- written by K1 block 0
    //   [wcount 4224 u32]                 <- fully written by K3 (plain stores)
    //   [plist 4224*64 uint4]             <- slots < wcount written by K3
    unsigned int*   pa_bits = (unsigned int*)(ws);
    unsigned int*   po_bits = (unsigned int*)(ws + 12800);
    unsigned int*   ccount  = (unsigned int*)(ws + 25600);
    unsigned short* clist   = (unsigned short*)(ws + 38400);
    int*    strip_off = (int*)(ws + 121600);             // 38400+83200
    float4* sAPI      = (float4*)(ws + 122112);          // +512 pad
    unsigned int* wcount = (unsigned int*)(ws + 256512); // +8400*16
    uint4*  plist     = (uint4*)(ws + 273408);           // 16B-aligned

    float* out = (float*)d_out;

    // 4 dispatches, 0 memsets, 0 contended atomics, 0 in-kernel cross-block sync:
    bin_kernel<<<2, 1024, 0, stream>>>(
        anchor_points, strip_off, sAPI, pa_bits);

    topk_kernel<<<TKBLK + ZBLK2, 256, 0, stream>>>(
        pred_scores, pred_bboxes, gt_labels, gt_bboxes, mask_gt,
        strip_off, sAPI, ccount, clist, out);

    dim3 rgrid(NCHUNK, BS);
    resolve_kernel<<<rgrid, 256, 0, stream>>>(
        pred_scores, pred_bboxes, gt_labels, gt_bboxes, ccount, clist,
        pa_bits, po_bits, wcount, plist, out);

    scatter_kernel<<<NWID / 4, 256, 0, stream>>>(
        wcount, plist, pa_bits, po_bits, out);
}